// Round 1
// baseline (3565.282 us; speedup 1.0000x reference)
//
#include <hip/hip_runtime.h>
#include <hip/hip_bf16.h>
#include <cstdint>

#define D_IN 512
#define D_HID 128

// ---------------- degree / dinv ----------------
__global__ __launch_bounds__(256) void k_deg_count(const int* __restrict__ dst,
                                                   float* __restrict__ deg, int E) {
    int e = blockIdx.x * 256 + threadIdx.x;
    if (e < E) atomicAdd(&deg[dst[e]], 1.0f);
}

__global__ __launch_bounds__(256) void k_make_dinv(float* __restrict__ deg, int N) {
    int i = blockIdx.x * 256 + threadIdx.x;
    if (i < N) deg[i] = rsqrtf(deg[i] + 1.0f);
}

// ---------------- GEMM: Y[N,128] = X[N,K] @ W[K,128], f32 ----------------
template <int K>
__global__ __launch_bounds__(256) void k_gemm(const float* __restrict__ X,
                                              const float* __restrict__ W,
                                              float* __restrict__ Y, int N) {
    __shared__ float Xs[32][36];    // 32 rows x 32 k (padded)
    __shared__ float Ws[32][128];   // 32 k x 128 cols
    const int tid = threadIdx.x;
    const int tc = tid & 31;        // col group: cols 4*tc .. 4*tc+3
    const int tr = tid >> 5;        // row group: rows 4*tr .. 4*tr+3
    const int row0 = blockIdx.x * 32;

    float acc[4][4];
#pragma unroll
    for (int i = 0; i < 4; ++i)
#pragma unroll
        for (int j = 0; j < 4; ++j) acc[i][j] = 0.f;

    for (int k0 = 0; k0 < K; k0 += 32) {
        // stage X tile: 32 rows x 32 k = 1024 floats, 4 per thread (float4 along k)
        {
            int r  = tid >> 3;
            int kk = (tid & 7) * 4;
            int row = row0 + r;
            float4 v = make_float4(0.f, 0.f, 0.f, 0.f);
            if (row < N) v = *(const float4*)&X[(size_t)row * K + k0 + kk];
            Xs[r][kk + 0] = v.x; Xs[r][kk + 1] = v.y;
            Xs[r][kk + 2] = v.z; Xs[r][kk + 3] = v.w;
        }
        // stage W tile: 32 k x 128 cols = 1024 float4, 4 per thread
        {
#pragma unroll
            for (int i = 0; i < 4; ++i) {
                int j  = tid + i * 256;   // float4 index, 32 float4 per k-row
                int wk = j >> 5;
                int wc = j & 31;
                float4 v = *(const float4*)&W[(size_t)(k0 + wk) * 128 + wc * 4];
                Ws[wk][wc * 4 + 0] = v.x; Ws[wk][wc * 4 + 1] = v.y;
                Ws[wk][wc * 4 + 2] = v.z; Ws[wk][wc * 4 + 3] = v.w;
            }
        }
        __syncthreads();
#pragma unroll
        for (int kk = 0; kk < 32; ++kk) {
            float a0 = Xs[tr * 4 + 0][kk];
            float a1 = Xs[tr * 4 + 1][kk];
            float a2 = Xs[tr * 4 + 2][kk];
            float a3 = Xs[tr * 4 + 3][kk];
            float4 b = *(const float4*)&Ws[kk][tc * 4];
            acc[0][0] += a0 * b.x; acc[0][1] += a0 * b.y; acc[0][2] += a0 * b.z; acc[0][3] += a0 * b.w;
            acc[1][0] += a1 * b.x; acc[1][1] += a1 * b.y; acc[1][2] += a1 * b.z; acc[1][3] += a1 * b.w;
            acc[2][0] += a2 * b.x; acc[2][1] += a2 * b.y; acc[2][2] += a2 * b.z; acc[2][3] += a2 * b.w;
            acc[3][0] += a3 * b.x; acc[3][1] += a3 * b.y; acc[3][2] += a3 * b.z; acc[3][3] += a3 * b.w;
        }
        __syncthreads();
    }
#pragma unroll
    for (int i = 0; i < 4; ++i) {
        int row = row0 + tr * 4 + i;
        if (row < N) {
            float4 v = make_float4(acc[i][0], acc[i][1], acc[i][2], acc[i][3]);
            *(float4*)&Y[(size_t)row * 128 + tc * 4] = v;
        }
    }
}

// ---------------- edge scatter: AGG[dst] += XW[src] * dinv[src]*dinv[dst] ----------------
__global__ __launch_bounds__(256) void k_scatter(const float* __restrict__ XW,
                                                 const float* __restrict__ dinv,
                                                 const int* __restrict__ src,
                                                 const int* __restrict__ dst,
                                                 float* __restrict__ AGG, int E) {
    int t = blockIdx.x * 256 + threadIdx.x;
    int e = t >> 5;                 // 32 threads per edge (float4 each)
    if (e >= E) return;
    int f4 = t & 31;
    int s = src[e], d = dst[e];
    float nrm = dinv[s] * dinv[d];
    float4 v = *(const float4*)&XW[(size_t)s * 128 + f4 * 4];
    float* out = &AGG[(size_t)d * 128 + f4 * 4];
    atomicAdd(out + 0, v.x * nrm);
    atomicAdd(out + 1, v.y * nrm);
    atomicAdd(out + 2, v.z * nrm);
    atomicAdd(out + 3, v.w * nrm);
}

// ---------------- layer1 tail: h = relu(LN(agg + xw*dinv^2 + b)) (in-place into XW) ----------------
__global__ __launch_bounds__(256) void k_self_ln_relu(const float* __restrict__ AGG,
                                                      float* __restrict__ XW,
                                                      const float* __restrict__ dinv,
                                                      const float* __restrict__ b,
                                                      const float* __restrict__ gamma,
                                                      const float* __restrict__ beta,
                                                      int N) {
    int node = (blockIdx.x * 256 + threadIdx.x) >> 6;
    int lane = threadIdx.x & 63;
    if (node >= N) return;
    float di = dinv[node];
    float d2 = di * di;
    size_t base = (size_t)node * 128;
    float v0 = AGG[base + lane]      + XW[base + lane]      * d2 + b[lane];
    float v1 = AGG[base + lane + 64] + XW[base + lane + 64] * d2 + b[lane + 64];
    float s  = v0 + v1;
    float sq = v0 * v0 + v1 * v1;
#pragma unroll
    for (int off = 32; off; off >>= 1) {
        s  += __shfl_xor(s, off);
        sq += __shfl_xor(sq, off);
    }
    float mu  = s * (1.f / 128.f);
    float var = sq * (1.f / 128.f) - mu * mu;
    float r   = rsqrtf(var + 1e-5f);
    float o0 = (v0 - mu) * r * gamma[lane] + beta[lane];
    float o1 = (v1 - mu) * r * gamma[lane + 64] + beta[lane + 64];
    XW[base + lane]      = fmaxf(o0, 0.f);
    XW[base + lane + 64] = fmaxf(o1, 0.f);
}

// ---------------- layers 2/3 tail: A = relu(A + XW*dinv^2 + b) ----------------
__global__ __launch_bounds__(256) void k_self_relu(float* __restrict__ A,
                                                   const float* __restrict__ XW,
                                                   const float* __restrict__ dinv,
                                                   const float* __restrict__ b, int N) {
    int t = blockIdx.x * 256 + threadIdx.x;
    int node = t >> 5;
    if (node >= N) return;
    int f4 = t & 31;
    float di = dinv[node];
    float d2 = di * di;
    size_t idx = (size_t)node * 128 + f4 * 4;
    float4 a = *(float4*)&A[idx];
    float4 x = *(const float4*)&XW[idx];
    float4 bb = *(const float4*)&b[f4 * 4];
    a.x = fmaxf(a.x + x.x * d2 + bb.x, 0.f);
    a.y = fmaxf(a.y + x.y * d2 + bb.y, 0.f);
    a.z = fmaxf(a.z + x.z * d2 + bb.z, 0.f);
    a.w = fmaxf(a.w + x.w * d2 + bb.w, 0.f);
    *(float4*)&A[idx] = a;
}

// ---------------- layer 4: xw4[i] = dot(H[i,:], W4) ----------------
__global__ __launch_bounds__(256) void k_dot_w4(const float* __restrict__ H,
                                                const float* __restrict__ W4,
                                                float* __restrict__ XW4, int N) {
    int node = (blockIdx.x * 256 + threadIdx.x) >> 6;
    int lane = threadIdx.x & 63;
    if (node >= N) return;
    size_t base = (size_t)node * 128;
    float s = H[base + lane] * W4[lane] + H[base + lane + 64] * W4[lane + 64];
#pragma unroll
    for (int off = 32; off; off >>= 1) s += __shfl_xor(s, off);
    if (lane == 0) XW4[node] = s;
}

__global__ __launch_bounds__(256) void k_scatter_scalar(const float* __restrict__ XW4,
                                                        const float* __restrict__ dinv,
                                                        const int* __restrict__ src,
                                                        const int* __restrict__ dst,
                                                        float* __restrict__ AGGS, int E) {
    int e = blockIdx.x * 256 + threadIdx.x;
    if (e >= E) return;
    int s = src[e], d = dst[e];
    atomicAdd(&AGGS[d], XW4[s] * dinv[s] * dinv[d]);
}

__global__ __launch_bounds__(256) void k_finalize(const float* __restrict__ AGGS,
                                                  const float* __restrict__ XW4,
                                                  const float* __restrict__ dinv,
                                                  const float* __restrict__ b4,
                                                  float* __restrict__ OUT, int N) {
    int i = blockIdx.x * 256 + threadIdx.x;
    if (i < N) OUT[i] = AGGS[i] + XW4[i] * dinv[i] * dinv[i] + b4[0];
}

extern "C" void kernel_launch(void* const* d_in, const int* in_sizes, int n_in,
                              void* d_out, int out_size, void* d_ws, size_t ws_size,
                              hipStream_t stream) {
    const float* x      = (const float*)d_in[0];
    const float* W1     = (const float*)d_in[1];
    const float* b1     = (const float*)d_in[2];
    const float* gamma1 = (const float*)d_in[3];
    const float* beta1  = (const float*)d_in[4];
    const float* W2     = (const float*)d_in[5];
    const float* b2     = (const float*)d_in[6];
    const float* W3     = (const float*)d_in[7];
    const float* b3     = (const float*)d_in[8];
    const float* W4     = (const float*)d_in[9];
    const float* b4     = (const float*)d_in[10];
    const int*   ei     = (const int*)d_in[11];

    const int N = in_sizes[0] / D_IN;     // 50000
    const int E = in_sizes[11] / 2;       // 625000
    const int* src = ei;
    const int* dst = ei + E;

    char* ws = (char*)d_ws;
    float* dinv = (float*)ws;                                   // N
    float* xw4  = (float*)(ws + (size_t)N * 4);                 // N
    float* aggs = (float*)(ws + (size_t)N * 8);                 // N
    float* bufA = (float*)(ws + (size_t)N * 12);                // N*128
    float* bufB = (float*)(ws + (size_t)N * 12 + (size_t)N * 512);

    const size_t rowBytes = (size_t)N * 128 * 4;

    // degrees -> dinv
    hipMemsetAsync(dinv, 0, (size_t)N * 4, stream);
    k_deg_count<<<(E + 255) / 256, 256, 0, stream>>>(dst, dinv, E);
    k_make_dinv<<<(N + 255) / 256, 256, 0, stream>>>(dinv, N);

    const int gemmGrid = (N + 31) / 32;
    const int scatGrid = (int)(((size_t)E * 32 + 255) / 256);
    const int waveGrid = (int)(((size_t)N * 64 + 255) / 256);
    const int pwGrid   = (int)(((size_t)N * 32 + 255) / 256);

    // ---- Layer 1: xw1 = x@W1 (A); agg (B); h1 = relu(LN(...)) -> A
    k_gemm<512><<<gemmGrid, 256, 0, stream>>>(x, W1, bufA, N);
    hipMemsetAsync(bufB, 0, rowBytes, stream);
    k_scatter<<<scatGrid, 256, 0, stream>>>(bufA, dinv, src, dst, bufB, E);
    k_self_ln_relu<<<waveGrid, 256, 0, stream>>>(bufB, bufA, dinv, b1, gamma1, beta1, N);

    // ---- Layer 2: xw2 = h1@W2 (B); agg (A); h2 = relu(...) -> A
    k_gemm<128><<<gemmGrid, 256, 0, stream>>>(bufA, W2, bufB, N);
    hipMemsetAsync(bufA, 0, rowBytes, stream);
    k_scatter<<<scatGrid, 256, 0, stream>>>(bufB, dinv, src, dst, bufA, E);
    k_self_relu<<<pwGrid, 256, 0, stream>>>(bufA, bufB, dinv, b2, N);

    // ---- Layer 3
    k_gemm<128><<<gemmGrid, 256, 0, stream>>>(bufA, W3, bufB, N);
    hipMemsetAsync(bufA, 0, rowBytes, stream);
    k_scatter<<<scatGrid, 256, 0, stream>>>(bufB, dinv, src, dst, bufA, E);
    k_self_relu<<<pwGrid, 256, 0, stream>>>(bufA, bufB, dinv, b3, N);

    // ---- Layer 4: scalar
    k_dot_w4<<<waveGrid, 256, 0, stream>>>(bufA, W4, xw4, N);
    hipMemsetAsync(aggs, 0, (size_t)N * 4, stream);
    k_scatter_scalar<<<(E + 255) / 256, 256, 0, stream>>>(xw4, dinv, src, dst, aggs, E);
    k_finalize<<<(N + 255) / 256, 256, 0, stream>>>(aggs, xw4, dinv, b4, (float*)d_out, N);
}

// Round 3
// 532.358 us; speedup vs baseline: 6.6972x; 6.6972x over previous
//
#include <hip/hip_runtime.h>
#include <hip/hip_bf16.h>
#include <cstdint>

#define D_IN 512
#define D_HID 128

// ================= CSR build =================
__global__ __launch_bounds__(256) void k_deg_int(const int* __restrict__ dst,
                                                 int* __restrict__ deg, int E) {
    int e = blockIdx.x * 256 + threadIdx.x;
    if (e < E) atomicAdd(&deg[dst[e]], 1);
}

// per-block exclusive scan of degrees; block sums out
__global__ __launch_bounds__(256) void k_scan_block(const int* __restrict__ deg,
                                                    int* __restrict__ rowptr,
                                                    int* __restrict__ bsum, int N) {
    __shared__ int sh[256];
    int i = blockIdx.x * 256 + threadIdx.x;
    int v = (i < N) ? deg[i] : 0;
    sh[threadIdx.x] = v;
    __syncthreads();
#pragma unroll
    for (int off = 1; off < 256; off <<= 1) {
        int t = (threadIdx.x >= off) ? sh[threadIdx.x - off] : 0;
        __syncthreads();
        sh[threadIdx.x] += t;
        __syncthreads();
    }
    int incl = sh[threadIdx.x];
    if (i < N) rowptr[i] = incl - v;          // local exclusive
    if (threadIdx.x == 255) bsum[blockIdx.x] = incl;
}

// single-block exclusive scan of block sums (P <= 256)
__global__ __launch_bounds__(256) void k_scan_partials(int* __restrict__ bsum, int P) {
    __shared__ int sh[256];
    int v = (threadIdx.x < P) ? bsum[threadIdx.x] : 0;
    sh[threadIdx.x] = v;
    __syncthreads();
#pragma unroll
    for (int off = 1; off < 256; off <<= 1) {
        int t = (threadIdx.x >= off) ? sh[threadIdx.x - off] : 0;
        __syncthreads();
        sh[threadIdx.x] += t;
        __syncthreads();
    }
    if (threadIdx.x < P) bsum[threadIdx.x] = sh[threadIdx.x] - v;  // exclusive
}

// rowptr += block offset; cursor = rowptr; dinv = rsqrt(deg+1); rowptr[N] = E
__global__ __launch_bounds__(256) void k_apply_offset(int* __restrict__ rowptr,
                                                      const int* __restrict__ bsum,
                                                      int* __restrict__ deg_cursor,
                                                      float* __restrict__ dinv,
                                                      int N, int E) {
    int i = blockIdx.x * 256 + threadIdx.x;
    if (i == 0) rowptr[N] = E;
    if (i >= N) return;
    int dv = deg_cursor[i];                  // degree (before overwrite)
    int rp = rowptr[i] + bsum[i >> 8];
    rowptr[i] = rp;
    deg_cursor[i] = rp;                      // cursor starts at row begin
    dinv[i] = rsqrtf((float)dv + 1.0f);
}

__global__ __launch_bounds__(256) void k_fill_csr(const int* __restrict__ src,
                                                  const int* __restrict__ dst,
                                                  int* __restrict__ cursor,
                                                  int* __restrict__ csr, int E) {
    int e = blockIdx.x * 256 + threadIdx.x;
    if (e >= E) return;
    int pos = atomicAdd(&cursor[dst[e]], 1);
    csr[pos] = src[e];
}

// ================= GEMM: Y[N,128] = X[N,K] @ W[K,128], f32 =================
template <int K>
__global__ __launch_bounds__(256) void k_gemm(const float* __restrict__ X,
                                              const float* __restrict__ W,
                                              float* __restrict__ Y, int N) {
    __shared__ float Xs[32][36];
    __shared__ float Ws[32][128];
    const int tid = threadIdx.x;
    const int tc = tid & 31;
    const int tr = tid >> 5;
    const int row0 = blockIdx.x * 32;

    float acc[4][4];
#pragma unroll
    for (int i = 0; i < 4; ++i)
#pragma unroll
        for (int j = 0; j < 4; ++j) acc[i][j] = 0.f;

    for (int k0 = 0; k0 < K; k0 += 32) {
        {
            int r  = tid >> 3;
            int kk = (tid & 7) * 4;
            int row = row0 + r;
            float4 v = make_float4(0.f, 0.f, 0.f, 0.f);
            if (row < N) v = *(const float4*)&X[(size_t)row * K + k0 + kk];
            Xs[r][kk + 0] = v.x; Xs[r][kk + 1] = v.y;
            Xs[r][kk + 2] = v.z; Xs[r][kk + 3] = v.w;
        }
        {
#pragma unroll
            for (int i = 0; i < 4; ++i) {
                int j  = tid + i * 256;
                int wk = j >> 5;
                int wc = j & 31;
                float4 v = *(const float4*)&W[(size_t)(k0 + wk) * 128 + wc * 4];
                Ws[wk][wc * 4 + 0] = v.x; Ws[wk][wc * 4 + 1] = v.y;
                Ws[wk][wc * 4 + 2] = v.z; Ws[wk][wc * 4 + 3] = v.w;
            }
        }
        __syncthreads();
#pragma unroll
        for (int kk = 0; kk < 32; ++kk) {
            float a0 = Xs[tr * 4 + 0][kk];
            float a1 = Xs[tr * 4 + 1][kk];
            float a2 = Xs[tr * 4 + 2][kk];
            float a3 = Xs[tr * 4 + 3][kk];
            float4 b = *(const float4*)&Ws[kk][tc * 4];
            acc[0][0] += a0 * b.x; acc[0][1] += a0 * b.y; acc[0][2] += a0 * b.z; acc[0][3] += a0 * b.w;
            acc[1][0] += a1 * b.x; acc[1][1] += a1 * b.y; acc[1][2] += a1 * b.z; acc[1][3] += a1 * b.w;
            acc[2][0] += a2 * b.x; acc[2][1] += a2 * b.y; acc[2][2] += a2 * b.z; acc[2][3] += a2 * b.w;
            acc[3][0] += a3 * b.x; acc[3][1] += a3 * b.y; acc[3][2] += a3 * b.z; acc[3][3] += a3 * b.w;
        }
        __syncthreads();
    }
#pragma unroll
    for (int i = 0; i < 4; ++i) {
        int row = row0 + tr * 4 + i;
        if (row < N) {
            float4 v = make_float4(acc[i][0], acc[i][1], acc[i][2], acc[i][3]);
            *(float4*)&Y[(size_t)row * 128 + tc * 4] = v;
        }
    }
}

// ================= fused gather + self-loop + bias + LN + ReLU (layer 1) =================
__global__ __launch_bounds__(256) void k_gather_ln_relu(const float* __restrict__ XW,
                                                        const int* __restrict__ rowptr,
                                                        const int* __restrict__ csr,
                                                        const float* __restrict__ dinv,
                                                        const float* __restrict__ b,
                                                        const float* __restrict__ gamma,
                                                        const float* __restrict__ beta,
                                                        float* __restrict__ H, int N) {
    int node = blockIdx.x * 4 + (threadIdx.x >> 6);
    int lane = threadIdx.x & 63;
    if (node >= N) return;
    float di = dinv[node];
    int beg = rowptr[node], end = rowptr[node + 1];
    float a0 = 0.f, a1 = 0.f;
    int j = beg;
    for (; j + 1 < end; j += 2) {
        int s0 = csr[j], s1 = csr[j + 1];
        float w0 = dinv[s0], w1 = dinv[s1];
        float x00 = XW[(size_t)s0 * 128 + lane];
        float x01 = XW[(size_t)s0 * 128 + 64 + lane];
        float x10 = XW[(size_t)s1 * 128 + lane];
        float x11 = XW[(size_t)s1 * 128 + 64 + lane];
        a0 += x00 * w0 + x10 * w1;
        a1 += x01 * w0 + x11 * w1;
    }
    if (j < end) {
        int s = csr[j];
        float w = dinv[s];
        a0 += XW[(size_t)s * 128 + lane] * w;
        a1 += XW[(size_t)s * 128 + 64 + lane] * w;
    }
    size_t base = (size_t)node * 128;
    float d2 = di * di;
    float v0 = a0 * di + XW[base + lane] * d2 + b[lane];
    float v1 = a1 * di + XW[base + 64 + lane] * d2 + b[lane + 64];
    float s  = v0 + v1;
    float sq = v0 * v0 + v1 * v1;
#pragma unroll
    for (int off = 32; off; off >>= 1) {
        s  += __shfl_xor(s, off);
        sq += __shfl_xor(sq, off);
    }
    float mu  = s * (1.f / 128.f);
    float var = sq * (1.f / 128.f) - mu * mu;
    float r   = rsqrtf(var + 1e-5f);
    float o0 = (v0 - mu) * r * gamma[lane] + beta[lane];
    float o1 = (v1 - mu) * r * gamma[lane + 64] + beta[lane + 64];
    H[base + lane]      = fmaxf(o0, 0.f);
    H[base + 64 + lane] = fmaxf(o1, 0.f);
}

// ================= fused gather + self-loop + bias + ReLU (layers 2/3) =================
__global__ __launch_bounds__(256) void k_gather_relu(const float* __restrict__ XW,
                                                     const int* __restrict__ rowptr,
                                                     const int* __restrict__ csr,
                                                     const float* __restrict__ dinv,
                                                     const float* __restrict__ b,
                                                     float* __restrict__ H, int N) {
    int node = blockIdx.x * 4 + (threadIdx.x >> 6);
    int lane = threadIdx.x & 63;
    if (node >= N) return;
    float di = dinv[node];
    int beg = rowptr[node], end = rowptr[node + 1];
    float a0 = 0.f, a1 = 0.f;
    int j = beg;
    for (; j + 1 < end; j += 2) {
        int s0 = csr[j], s1 = csr[j + 1];
        float w0 = dinv[s0], w1 = dinv[s1];
        float x00 = XW[(size_t)s0 * 128 + lane];
        float x01 = XW[(size_t)s0 * 128 + 64 + lane];
        float x10 = XW[(size_t)s1 * 128 + lane];
        float x11 = XW[(size_t)s1 * 128 + 64 + lane];
        a0 += x00 * w0 + x10 * w1;
        a1 += x01 * w0 + x11 * w1;
    }
    if (j < end) {
        int s = csr[j];
        float w = dinv[s];
        a0 += XW[(size_t)s * 128 + lane] * w;
        a1 += XW[(size_t)s * 128 + 64 + lane] * w;
    }
    size_t base = (size_t)node * 128;
    float d2 = di * di;
    float v0 = a0 * di + XW[base + lane] * d2 + b[lane];
    float v1 = a1 * di + XW[base + 64 + lane] * d2 + b[lane + 64];
    H[base + lane]      = fmaxf(v0, 0.f);
    H[base + 64 + lane] = fmaxf(v1, 0.f);
}

// ================= layer 4 =================
__global__ __launch_bounds__(256) void k_dot_w4(const float* __restrict__ H,
                                                const float* __restrict__ W4,
                                                float* __restrict__ XW4, int N) {
    int node = (blockIdx.x * 256 + threadIdx.x) >> 6;
    int lane = threadIdx.x & 63;
    if (node >= N) return;
    size_t base = (size_t)node * 128;
    float s = H[base + lane] * W4[lane] + H[base + lane + 64] * W4[lane + 64];
#pragma unroll
    for (int off = 32; off; off >>= 1) s += __shfl_xor(s, off);
    if (lane == 0) XW4[node] = s;
}

__global__ __launch_bounds__(256) void k_final_scalar(const float* __restrict__ XW4,
                                                      const int* __restrict__ rowptr,
                                                      const int* __restrict__ csr,
                                                      const float* __restrict__ dinv,
                                                      const float* __restrict__ b4,
                                                      float* __restrict__ OUT, int N) {
    int i = blockIdx.x * 256 + threadIdx.x;
    if (i >= N) return;
    float di = dinv[i];
    int beg = rowptr[i], end = rowptr[i + 1];
    float acc = 0.f;
    for (int j = beg; j < end; ++j) {
        int s = csr[j];
        acc += XW4[s] * dinv[s];
    }
    OUT[i] = acc * di + XW4[i] * di * di + b4[0];
}

// ================= launch =================
static inline size_t alignup(size_t x) { return (x + 255) & ~(size_t)255; }

extern "C" void kernel_launch(void* const* d_in, const int* in_sizes, int n_in,
                              void* d_out, int out_size, void* d_ws, size_t ws_size,
                              hipStream_t stream) {
    const float* x      = (const float*)d_in[0];
    const float* W1     = (const float*)d_in[1];
    const float* b1     = (const float*)d_in[2];
    const float* gamma1 = (const float*)d_in[3];
    const float* beta1  = (const float*)d_in[4];
    const float* W2     = (const float*)d_in[5];
    const float* b2     = (const float*)d_in[6];
    const float* W3     = (const float*)d_in[7];
    const float* b3     = (const float*)d_in[8];
    const float* W4     = (const float*)d_in[9];
    const float* b4     = (const float*)d_in[10];
    const int*   ei     = (const int*)d_in[11];

    const int N = in_sizes[0] / D_IN;     // 50000
    const int E = in_sizes[11] / 2;       // 625000
    const int* src = ei;
    const int* dst = ei + E;

    char* ws = (char*)d_ws;
    size_t off = 0;
    int*   deg_cur = (int*)(ws + off);  off += alignup((size_t)N * 4);
    int*   rowptr  = (int*)(ws + off);  off += alignup((size_t)(N + 1) * 4);
    int*   bsum    = (int*)(ws + off);  off += alignup(256 * 4);
    float* dinv    = (float*)(ws + off); off += alignup((size_t)N * 4);
    float* xw4     = (float*)(ws + off); off += alignup((size_t)N * 4);
    int*   csr     = (int*)(ws + off);  off += alignup((size_t)E * 4);
    float* bufA    = (float*)(ws + off); off += (size_t)N * 128 * 4;
    float* bufB    = (float*)(ws + off);

    const int scanBlocks = (N + 255) / 256;   // 196

    // ---- CSR build (once per call, reused by all 4 layers)
    hipMemsetAsync(deg_cur, 0, (size_t)N * 4, stream);
    k_deg_int<<<(E + 255) / 256, 256, 0, stream>>>(dst, deg_cur, E);
    k_scan_block<<<scanBlocks, 256, 0, stream>>>(deg_cur, rowptr, bsum, N);
    k_scan_partials<<<1, 256, 0, stream>>>(bsum, scanBlocks);
    k_apply_offset<<<scanBlocks, 256, 0, stream>>>(rowptr, bsum, deg_cur, dinv, N, E);
    k_fill_csr<<<(E + 255) / 256, 256, 0, stream>>>(src, dst, deg_cur, csr, E);

    const int gemmGrid   = (N + 31) / 32;
    const int gatherGrid = (N + 3) / 4;
    const int waveGrid   = (int)(((size_t)N * 64 + 255) / 256);

    // ---- Layer 1
    k_gemm<512><<<gemmGrid, 256, 0, stream>>>(x, W1, bufA, N);
    k_gather_ln_relu<<<gatherGrid, 256, 0, stream>>>(bufA, rowptr, csr, dinv,
                                                     b1, gamma1, beta1, bufB, N);
    // ---- Layer 2
    k_gemm<128><<<gemmGrid, 256, 0, stream>>>(bufB, W2, bufA, N);
    k_gather_relu<<<gatherGrid, 256, 0, stream>>>(bufA, rowptr, csr, dinv, b2, bufB, N);
    // ---- Layer 3
    k_gemm<128><<<gemmGrid, 256, 0, stream>>>(bufB, W3, bufA, N);
    k_gather_relu<<<gatherGrid, 256, 0, stream>>>(bufA, rowptr, csr, dinv, b3, bufB, N);
    // ---- Layer 4
    k_dot_w4<<<waveGrid, 256, 0, stream>>>(bufB, W4, xw4, N);
    k_final_scalar<<<(N + 255) / 256, 256, 0, stream>>>(xw4, rowptr, csr, dinv,
                                                        b4, (float*)d_out, N);
}

// Round 4
// 399.043 us; speedup vs baseline: 8.9346x; 1.3341x over previous
//
#include <hip/hip_runtime.h>
#include <hip/hip_bf16.h>
#include <cstdint>

#define D_IN 512
#define D_HID 128

typedef unsigned short u16;
typedef __attribute__((ext_vector_type(8))) short short8;
typedef __attribute__((ext_vector_type(4))) float f32x4;

__device__ __forceinline__ u16 f2bf(float f) {
    unsigned u = __float_as_uint(f);
    u = (u + 0x7FFFu + ((u >> 16) & 1u)) >> 16;
    return (u16)u;
}
__device__ __forceinline__ float bf_lo(unsigned u) { return __uint_as_float(u << 16); }
__device__ __forceinline__ float bf_hi(unsigned u) { return __uint_as_float(u & 0xFFFF0000u); }

// ================= CSR build =================
__global__ __launch_bounds__(256) void k_deg_int(const int* __restrict__ dst,
                                                 int* __restrict__ deg, int E) {
    int e = blockIdx.x * 256 + threadIdx.x;
    if (e < E) atomicAdd(&deg[dst[e]], 1);
}

__global__ __launch_bounds__(256) void k_scan_block(const int* __restrict__ deg,
                                                    int* __restrict__ rowptr,
                                                    int* __restrict__ bsum, int N) {
    __shared__ int sh[256];
    int i = blockIdx.x * 256 + threadIdx.x;
    int v = (i < N) ? deg[i] : 0;
    sh[threadIdx.x] = v;
    __syncthreads();
#pragma unroll
    for (int off = 1; off < 256; off <<= 1) {
        int t = (threadIdx.x >= off) ? sh[threadIdx.x - off] : 0;
        __syncthreads();
        sh[threadIdx.x] += t;
        __syncthreads();
    }
    int incl = sh[threadIdx.x];
    if (i < N) rowptr[i] = incl - v;
    if (threadIdx.x == 255) bsum[blockIdx.x] = incl;
}

__global__ __launch_bounds__(256) void k_scan_partials(int* __restrict__ bsum, int P) {
    __shared__ int sh[256];
    int v = (threadIdx.x < P) ? bsum[threadIdx.x] : 0;
    sh[threadIdx.x] = v;
    __syncthreads();
#pragma unroll
    for (int off = 1; off < 256; off <<= 1) {
        int t = (threadIdx.x >= off) ? sh[threadIdx.x - off] : 0;
        __syncthreads();
        sh[threadIdx.x] += t;
        __syncthreads();
    }
    if (threadIdx.x < P) bsum[threadIdx.x] = sh[threadIdx.x] - v;
}

__global__ __launch_bounds__(256) void k_apply_offset(int* __restrict__ rowptr,
                                                      const int* __restrict__ bsum,
                                                      int* __restrict__ deg_cursor,
                                                      float* __restrict__ dinv,
                                                      int N, int E) {
    int i = blockIdx.x * 256 + threadIdx.x;
    if (i == 0) rowptr[N] = E;
    if (i >= N) return;
    int dv = deg_cursor[i];
    int rp = rowptr[i] + bsum[i >> 8];
    rowptr[i] = rp;
    deg_cursor[i] = rp;
    dinv[i] = rsqrtf((float)dv + 1.0f);
}

__global__ __launch_bounds__(256) void k_fill_csr(const int* __restrict__ src,
                                                  const int* __restrict__ dst,
                                                  int* __restrict__ cursor,
                                                  int* __restrict__ csr, int E) {
    int e = blockIdx.x * 256 + threadIdx.x;
    if (e >= E) return;
    int pos = atomicAdd(&cursor[dst[e]], 1);
    csr[pos] = src[e];
}

// ================= weight convert + transpose: WT[c][k] = bf16(W[k][c]) =================
__global__ __launch_bounds__(256) void k_wt(const float* __restrict__ W,
                                            u16* __restrict__ WT, int K) {
    int t = blockIdx.x * 256 + threadIdx.x;
    if (t >= 128 * K) return;
    int c = t / K, k = t - c * K;
    WT[t] = f2bf(W[(size_t)k * 128 + c]);
}

// ================= MFMA GEMM: Y[N,128](bf16) = X[N,K](f32) @ W[K,128] =================
// block = 64 rows x 128 cols, 4 waves (16 rows each), K-step 32
template <int K>
__global__ __launch_bounds__(256) void k_gemm_mfma(const float* __restrict__ X,
                                                   const u16* __restrict__ WT,
                                                   u16* __restrict__ Y, int N) {
    __shared__ u16 Xs[64 * 40];    // rows padded 32->40 (bank spread)
    __shared__ u16 Ws[128 * 40];   // col-major (col, k), padded
    const int tid = threadIdx.x;
    const int wv = tid >> 6;
    const int lane = tid & 63;
    const int row0 = blockIdx.x * 64;
    const int rsel = lane & 15;
    const int kgrp = (lane >> 4) * 8;

    f32x4 acc[8];
#pragma unroll
    for (int c = 0; c < 8; ++c) acc[c] = (f32x4){0.f, 0.f, 0.f, 0.f};

    for (int k0 = 0; k0 < K; k0 += 32) {
        // stage X tile (64 x 32) -> bf16
        {
            int r = tid >> 2;
            int kk = (tid & 3) * 8;
            int row = row0 + r;
            float v[8];
            if (row < N) {
                float4 p0 = *(const float4*)&X[(size_t)row * K + k0 + kk];
                float4 p1 = *(const float4*)&X[(size_t)row * K + k0 + kk + 4];
                v[0] = p0.x; v[1] = p0.y; v[2] = p0.z; v[3] = p0.w;
                v[4] = p1.x; v[5] = p1.y; v[6] = p1.z; v[7] = p1.w;
            } else {
#pragma unroll
                for (int i = 0; i < 8; ++i) v[i] = 0.f;
            }
            union { u16 us[8]; short8 v8; } tmp;
#pragma unroll
            for (int i = 0; i < 8; ++i) tmp.us[i] = f2bf(v[i]);
            *(short8*)&Xs[r * 40 + kk] = tmp.v8;
        }
        // stage W^T tile (128 cols x 32 k), already bf16
        {
            int col = tid >> 1;
            int kh = (tid & 1) * 16;
            const u16* g = &WT[(size_t)col * K + k0 + kh];
            u16* d = &Ws[col * 40 + kh];
            *(short8*)d = *(const short8*)g;
            *(short8*)(d + 8) = *(const short8*)(g + 8);
        }
        __syncthreads();
        short8 a = *(const short8*)&Xs[(wv * 16 + rsel) * 40 + kgrp];
#pragma unroll
        for (int c = 0; c < 8; ++c) {
            short8 b = *(const short8*)&Ws[(c * 16 + rsel) * 40 + kgrp];
            acc[c] = __builtin_amdgcn_mfma_f32_16x16x32_bf16(a, b, acc[c], 0, 0, 0);
        }
        __syncthreads();
    }
    // epilogue: D layout col=lane&15, row=(lane>>4)*4+reg
#pragma unroll
    for (int r = 0; r < 4; ++r) {
        int row = row0 + wv * 16 + (lane >> 4) * 4 + r;
        if (row < N) {
#pragma unroll
            for (int c = 0; c < 8; ++c)
                Y[(size_t)row * 128 + c * 16 + rsel] = f2bf(acc[c][r]);
        }
    }
}

// ================= gather (bf16 XW) + self + bias + LN + ReLU -> H f32 (layer 1) =================
__global__ __launch_bounds__(256) void k_gather_ln_relu(const u16* __restrict__ XW,
                                                        const int* __restrict__ rowptr,
                                                        const int* __restrict__ csr,
                                                        const float* __restrict__ dinv,
                                                        const float* __restrict__ b,
                                                        const float* __restrict__ gamma,
                                                        const float* __restrict__ beta,
                                                        float* __restrict__ H, int N) {
    int node = blockIdx.x * 4 + (threadIdx.x >> 6);
    int lane = threadIdx.x & 63;
    if (node >= N) return;
    float di = dinv[node];
    int beg = rowptr[node], end = rowptr[node + 1];
    const int loff = 2 * lane;
    float a0 = 0.f, a1 = 0.f;
    int j = beg;
    for (; j + 3 < end; j += 4) {
        int s0 = csr[j], s1 = csr[j + 1], s2 = csr[j + 2], s3 = csr[j + 3];
        float w0 = dinv[s0], w1 = dinv[s1], w2 = dinv[s2], w3 = dinv[s3];
        unsigned u0 = *(const unsigned*)&XW[(size_t)s0 * 128 + loff];
        unsigned u1 = *(const unsigned*)&XW[(size_t)s1 * 128 + loff];
        unsigned u2 = *(const unsigned*)&XW[(size_t)s2 * 128 + loff];
        unsigned u3 = *(const unsigned*)&XW[(size_t)s3 * 128 + loff];
        a0 += bf_lo(u0) * w0 + bf_lo(u1) * w1 + bf_lo(u2) * w2 + bf_lo(u3) * w3;
        a1 += bf_hi(u0) * w0 + bf_hi(u1) * w1 + bf_hi(u2) * w2 + bf_hi(u3) * w3;
    }
    for (; j < end; ++j) {
        int s = csr[j];
        float w = dinv[s];
        unsigned u = *(const unsigned*)&XW[(size_t)s * 128 + loff];
        a0 += bf_lo(u) * w;
        a1 += bf_hi(u) * w;
    }
    unsigned us = *(const unsigned*)&XW[(size_t)node * 128 + loff];
    float d2 = di * di;
    float2 bb = *(const float2*)&b[loff];
    float v0 = a0 * di + bf_lo(us) * d2 + bb.x;
    float v1 = a1 * di + bf_hi(us) * d2 + bb.y;
    float s = v0 + v1;
    float sq = v0 * v0 + v1 * v1;
#pragma unroll
    for (int off = 32; off; off >>= 1) {
        s  += __shfl_xor(s, off);
        sq += __shfl_xor(sq, off);
    }
    float mu  = s * (1.f / 128.f);
    float var = sq * (1.f / 128.f) - mu * mu;
    float rr  = rsqrtf(var + 1e-5f);
    float2 gg = *(const float2*)&gamma[loff];
    float2 be = *(const float2*)&beta[loff];
    float o0 = fmaxf((v0 - mu) * rr * gg.x + be.x, 0.f);
    float o1 = fmaxf((v1 - mu) * rr * gg.y + be.y, 0.f);
    *(float2*)&H[(size_t)node * 128 + loff] = make_float2(o0, o1);
}

// ================= gather + self + bias + ReLU -> H f32 (layer 2) =================
__global__ __launch_bounds__(256) void k_gather_relu(const u16* __restrict__ XW,
                                                     const int* __restrict__ rowptr,
                                                     const int* __restrict__ csr,
                                                     const float* __restrict__ dinv,
                                                     const float* __restrict__ b,
                                                     float* __restrict__ H, int N) {
    int node = blockIdx.x * 4 + (threadIdx.x >> 6);
    int lane = threadIdx.x & 63;
    if (node >= N) return;
    float di = dinv[node];
    int beg = rowptr[node], end = rowptr[node + 1];
    const int loff = 2 * lane;
    float a0 = 0.f, a1 = 0.f;
    int j = beg;
    for (; j + 3 < end; j += 4) {
        int s0 = csr[j], s1 = csr[j + 1], s2 = csr[j + 2], s3 = csr[j + 3];
        float w0 = dinv[s0], w1 = dinv[s1], w2 = dinv[s2], w3 = dinv[s3];
        unsigned u0 = *(const unsigned*)&XW[(size_t)s0 * 128 + loff];
        unsigned u1 = *(const unsigned*)&XW[(size_t)s1 * 128 + loff];
        unsigned u2 = *(const unsigned*)&XW[(size_t)s2 * 128 + loff];
        unsigned u3 = *(const unsigned*)&XW[(size_t)s3 * 128 + loff];
        a0 += bf_lo(u0) * w0 + bf_lo(u1) * w1 + bf_lo(u2) * w2 + bf_lo(u3) * w3;
        a1 += bf_hi(u0) * w0 + bf_hi(u1) * w1 + bf_hi(u2) * w2 + bf_hi(u3) * w3;
    }
    for (; j < end; ++j) {
        int s = csr[j];
        float w = dinv[s];
        unsigned u = *(const unsigned*)&XW[(size_t)s * 128 + loff];
        a0 += bf_lo(u) * w;
        a1 += bf_hi(u) * w;
    }
    unsigned us = *(const unsigned*)&XW[(size_t)node * 128 + loff];
    float d2 = di * di;
    float2 bb = *(const float2*)&b[loff];
    float v0 = fmaxf(a0 * di + bf_lo(us) * d2 + bb.x, 0.f);
    float v1 = fmaxf(a1 * di + bf_hi(us) * d2 + bb.y, 0.f);
    *(float2*)&H[(size_t)node * 128 + loff] = make_float2(v0, v1);
}

// ================= layer 3 gather + ReLU fused with layer-4 W4 dot -> xw4 f32 =================
__global__ __launch_bounds__(256) void k_gather_dot(const u16* __restrict__ XW,
                                                    const int* __restrict__ rowptr,
                                                    const int* __restrict__ csr,
                                                    const float* __restrict__ dinv,
                                                    const float* __restrict__ b,
                                                    const float* __restrict__ W4,
                                                    float* __restrict__ XW4, int N) {
    int node = blockIdx.x * 4 + (threadIdx.x >> 6);
    int lane = threadIdx.x & 63;
    if (node >= N) return;
    float di = dinv[node];
    int beg = rowptr[node], end = rowptr[node + 1];
    const int loff = 2 * lane;
    float a0 = 0.f, a1 = 0.f;
    int j = beg;
    for (; j + 3 < end; j += 4) {
        int s0 = csr[j], s1 = csr[j + 1], s2 = csr[j + 2], s3 = csr[j + 3];
        float w0 = dinv[s0], w1 = dinv[s1], w2 = dinv[s2], w3 = dinv[s3];
        unsigned u0 = *(const unsigned*)&XW[(size_t)s0 * 128 + loff];
        unsigned u1 = *(const unsigned*)&XW[(size_t)s1 * 128 + loff];
        unsigned u2 = *(const unsigned*)&XW[(size_t)s2 * 128 + loff];
        unsigned u3 = *(const unsigned*)&XW[(size_t)s3 * 128 + loff];
        a0 += bf_lo(u0) * w0 + bf_lo(u1) * w1 + bf_lo(u2) * w2 + bf_lo(u3) * w3;
        a1 += bf_hi(u0) * w0 + bf_hi(u1) * w1 + bf_hi(u2) * w2 + bf_hi(u3) * w3;
    }
    for (; j < end; ++j) {
        int s = csr[j];
        float w = dinv[s];
        unsigned u = *(const unsigned*)&XW[(size_t)s * 128 + loff];
        a0 += bf_lo(u) * w;
        a1 += bf_hi(u) * w;
    }
    unsigned us = *(const unsigned*)&XW[(size_t)node * 128 + loff];
    float d2 = di * di;
    float2 bb = *(const float2*)&b[loff];
    float v0 = fmaxf(a0 * di + bf_lo(us) * d2 + bb.x, 0.f);
    float v1 = fmaxf(a1 * di + bf_hi(us) * d2 + bb.y, 0.f);
    float2 w4v = *(const float2*)&W4[loff];
    float t = v0 * w4v.x + v1 * w4v.y;
#pragma unroll
    for (int off = 32; off; off >>= 1) t += __shfl_xor(t, off);
    if (lane == 0) XW4[node] = t;
}

// ================= final: out = agg(xw4)*norm + self + b4 =================
__global__ __launch_bounds__(256) void k_final_scalar(const float* __restrict__ XW4,
                                                      const int* __restrict__ rowptr,
                                                      const int* __restrict__ csr,
                                                      const float* __restrict__ dinv,
                                                      const float* __restrict__ b4,
                                                      float* __restrict__ OUT, int N) {
    int i = blockIdx.x * 256 + threadIdx.x;
    if (i >= N) return;
    float di = dinv[i];
    int beg = rowptr[i], end = rowptr[i + 1];
    float acc = 0.f;
    for (int j = beg; j < end; ++j) {
        int s = csr[j];
        acc += XW4[s] * dinv[s];
    }
    OUT[i] = acc * di + XW4[i] * di * di + b4[0];
}

// ================= launch =================
static inline size_t alignup(size_t x) { return (x + 255) & ~(size_t)255; }

extern "C" void kernel_launch(void* const* d_in, const int* in_sizes, int n_in,
                              void* d_out, int out_size, void* d_ws, size_t ws_size,
                              hipStream_t stream) {
    const float* x      = (const float*)d_in[0];
    const float* W1     = (const float*)d_in[1];
    const float* b1     = (const float*)d_in[2];
    const float* gamma1 = (const float*)d_in[3];
    const float* beta1  = (const float*)d_in[4];
    const float* W2     = (const float*)d_in[5];
    const float* b2     = (const float*)d_in[6];
    const float* W3     = (const float*)d_in[7];
    const float* b3     = (const float*)d_in[8];
    const float* W4     = (const float*)d_in[9];
    const float* b4     = (const float*)d_in[10];
    const int*   ei     = (const int*)d_in[11];

    const int N = in_sizes[0] / D_IN;     // 50000
    const int E = in_sizes[11] / 2;       // 625000
    const int* src = ei;
    const int* dst = ei + E;

    char* ws = (char*)d_ws;
    size_t off = 0;
    int*   deg_cur = (int*)(ws + off);   off += alignup((size_t)N * 4);
    int*   rowptr  = (int*)(ws + off);   off += alignup((size_t)(N + 1) * 4);
    int*   bsum    = (int*)(ws + off);   off += alignup(256 * 4);
    float* dinv    = (float*)(ws + off); off += alignup((size_t)N * 4);
    float* xw4     = (float*)(ws + off); off += alignup((size_t)N * 4);
    int*   csr     = (int*)(ws + off);   off += alignup((size_t)E * 4);
    u16*   WT1     = (u16*)(ws + off);   off += alignup((size_t)128 * 512 * 2);
    u16*   WT2     = (u16*)(ws + off);   off += alignup((size_t)128 * 128 * 2);
    u16*   WT3     = (u16*)(ws + off);   off += alignup((size_t)128 * 128 * 2);
    u16*   XW      = (u16*)(ws + off);   off += alignup((size_t)N * 128 * 2);
    float* H       = (float*)(ws + off);

    const int scanBlocks = (N + 255) / 256;

    // ---- CSR build
    hipMemsetAsync(deg_cur, 0, (size_t)N * 4, stream);
    k_deg_int<<<(E + 255) / 256, 256, 0, stream>>>(dst, deg_cur, E);
    k_scan_block<<<scanBlocks, 256, 0, stream>>>(deg_cur, rowptr, bsum, N);
    k_scan_partials<<<1, 256, 0, stream>>>(bsum, scanBlocks);
    k_apply_offset<<<scanBlocks, 256, 0, stream>>>(rowptr, bsum, deg_cur, dinv, N, E);
    k_fill_csr<<<(E + 255) / 256, 256, 0, stream>>>(src, dst, deg_cur, csr, E);

    // ---- weights -> bf16 transposed
    k_wt<<<(128 * 512 + 255) / 256, 256, 0, stream>>>(W1, WT1, 512);
    k_wt<<<(128 * 128 + 255) / 256, 256, 0, stream>>>(W2, WT2, 128);
    k_wt<<<(128 * 128 + 255) / 256, 256, 0, stream>>>(W3, WT3, 128);

    const int gemmGrid   = (N + 63) / 64;
    const int gatherGrid = (N + 3) / 4;

    // ---- Layer 1
    k_gemm_mfma<512><<<gemmGrid, 256, 0, stream>>>(x, WT1, XW, N);
    k_gather_ln_relu<<<gatherGrid, 256, 0, stream>>>(XW, rowptr, csr, dinv,
                                                     b1, gamma1, beta1, H, N);
    // ---- Layer 2
    k_gemm_mfma<128><<<gemmGrid, 256, 0, stream>>>(H, WT2, XW, N);
    k_gather_relu<<<gatherGrid, 256, 0, stream>>>(XW, rowptr, csr, dinv, b2, H, N);
    // ---- Layer 3 (+ fused W4 dot)
    k_gemm_mfma<128><<<gemmGrid, 256, 0, stream>>>(H, WT3, XW, N);
    k_gather_dot<<<gatherGrid, 256, 0, stream>>>(XW, rowptr, csr, dinv, b3, W4, xw4, N);
    // ---- Layer 4 aggregate
    k_final_scalar<<<(N + 255) / 256, 256, 0, stream>>>(xw4, rowptr, csr, dinv,
                                                        b4, (float*)d_out, N);
}

// Round 9
// 375.355 us; speedup vs baseline: 9.4984x; 1.0631x over previous
//
#include <hip/hip_runtime.h>
#include <hip/hip_bf16.h>
#include <cstdint>

#define D_IN 512
#define D_HID 128

typedef unsigned short u16;
typedef unsigned int u32;
typedef __attribute__((ext_vector_type(8))) short short8;
typedef __attribute__((ext_vector_type(4))) float f32x4;

__device__ __forceinline__ u16 f2bf(float f) {
    u32 u = __float_as_uint(f);
    u = (u + 0x7FFFu + ((u >> 16) & 1u)) >> 16;
    return (u16)u;
}
__device__ __forceinline__ float bfc(short x) {
    return __uint_as_float(((u32)(u16)x) << 16);
}

// ================= CSR build =================
__global__ __launch_bounds__(256) void k_deg_int(const int* __restrict__ dst,
                                                 int* __restrict__ deg, int E) {
    int e = blockIdx.x * 256 + threadIdx.x;
    if (e < E) atomicAdd(&deg[dst[e]], 1);
}

__global__ __launch_bounds__(256) void k_scan_block(const int* __restrict__ deg,
                                                    int* __restrict__ rowptr,
                                                    int* __restrict__ bsum, int N) {
    __shared__ int sh[256];
    int i = blockIdx.x * 256 + threadIdx.x;
    int v = (i < N) ? deg[i] : 0;
    sh[threadIdx.x] = v;
    __syncthreads();
#pragma unroll
    for (int off = 1; off < 256; off <<= 1) {
        int t = (threadIdx.x >= off) ? sh[threadIdx.x - off] : 0;
        __syncthreads();
        sh[threadIdx.x] += t;
        __syncthreads();
    }
    int incl = sh[threadIdx.x];
    if (i < N) rowptr[i] = incl - v;
    if (threadIdx.x == 255) bsum[blockIdx.x] = incl;
}

__global__ __launch_bounds__(256) void k_scan_partials(int* __restrict__ bsum, int P) {
    __shared__ int sh[256];
    int v = (threadIdx.x < P) ? bsum[threadIdx.x] : 0;
    sh[threadIdx.x] = v;
    __syncthreads();
#pragma unroll
    for (int off = 1; off < 256; off <<= 1) {
        int t = (threadIdx.x >= off) ? sh[threadIdx.x - off] : 0;
        __syncthreads();
        sh[threadIdx.x] += t;
        __syncthreads();
    }
    if (threadIdx.x < P) bsum[threadIdx.x] = sh[threadIdx.x] - v;
}

__global__ __launch_bounds__(256) void k_apply_offset(int* __restrict__ rowptr,
                                                      const int* __restrict__ bsum,
                                                      int* __restrict__ deg_cursor,
                                                      float* __restrict__ dinv,
                                                      int N, int E) {
    int i = blockIdx.x * 256 + threadIdx.x;
    if (i == 0) rowptr[N] = E;
    if (i >= N) return;
    int dv = deg_cursor[i];
    int rp = rowptr[i] + bsum[i >> 8];
    rowptr[i] = rp;
    deg_cursor[i] = rp;
    dinv[i] = rsqrtf((float)dv + 1.0f);
}

__global__ __launch_bounds__(256) void k_fill_csr(const int* __restrict__ src,
                                                  const int* __restrict__ dst,
                                                  int* __restrict__ cursor,
                                                  int* __restrict__ csr, int E) {
    int e = blockIdx.x * 256 + threadIdx.x;
    if (e >= E) return;
    int pos = atomicAdd(&cursor[dst[e]], 1);
    csr[pos] = src[e];
}

// ============ all weights -> bf16 transposed, one launch ============
// WT[c][k] = bf16(W[k][c])
__global__ __launch_bounds__(256) void k_wt_all(const float* __restrict__ W1,
                                                const float* __restrict__ W2,
                                                const float* __restrict__ W3,
                                                u16* __restrict__ WT1,
                                                u16* __restrict__ WT2,
                                                u16* __restrict__ WT3) {
    int t = blockIdx.x * 256 + threadIdx.x;
    if (t < 65536) {                       // 128 cols x 512 k
        int c = t >> 9, k = t & 511;
        WT1[t] = f2bf(W1[(size_t)k * 128 + c]);
    } else if (t < 65536 + 16384) {
        int u = t - 65536;
        int c = u >> 7, k = u & 127;
        WT2[u] = f2bf(W2[(size_t)k * 128 + c]);
    } else if (t < 65536 + 32768) {
        int u = t - 65536 - 16384;
        int c = u >> 7, k = u & 127;
        WT3[u] = f2bf(W3[(size_t)k * 128 + c]);
    }
}

// ================= MFMA GEMM: Y[N,128](bf16) = X[N,K] @ W[K,128] =================
// block = 64 rows x 128 cols, 4 waves (16 rows each), K-step 32
// TI = float (layer 1, converts) or u16 (layers 2/3, straight copy)
template <int K, typename TI>
__global__ __launch_bounds__(256) void k_gemm_mfma(const TI* __restrict__ X,
                                                   const u16* __restrict__ WT,
                                                   u16* __restrict__ Y, int N) {
    __shared__ u16 Xs[64 * 40];
    __shared__ u16 Ws[128 * 40];
    const int tid = threadIdx.x;
    const int wv = tid >> 6;
    const int lane = tid & 63;
    const int row0 = blockIdx.x * 64;
    const int rsel = lane & 15;
    const int kgrp = (lane >> 4) * 8;

    f32x4 acc[8];
#pragma unroll
    for (int c = 0; c < 8; ++c) acc[c] = (f32x4){0.f, 0.f, 0.f, 0.f};

    for (int k0 = 0; k0 < K; k0 += 32) {
        // stage X tile (64 rows x 32 k) -> bf16 LDS
        {
            int r = tid >> 2;
            int kk = (tid & 3) * 8;
            int row = row0 + r;
            if constexpr (sizeof(TI) == 4) {
                float v[8];
                if (row < N) {
                    float4 p0 = *(const float4*)&X[(size_t)row * K + k0 + kk];
                    float4 p1 = *(const float4*)&X[(size_t)row * K + k0 + kk + 4];
                    v[0] = p0.x; v[1] = p0.y; v[2] = p0.z; v[3] = p0.w;
                    v[4] = p1.x; v[5] = p1.y; v[6] = p1.z; v[7] = p1.w;
                } else {
#pragma unroll
                    for (int i = 0; i < 8; ++i) v[i] = 0.f;
                }
                union { u16 us[8]; short8 v8; } tmp;
#pragma unroll
                for (int i = 0; i < 8; ++i) tmp.us[i] = f2bf(v[i]);
                *(short8*)&Xs[r * 40 + kk] = tmp.v8;
            } else {
                short8 v8 = {};
                if (row < N) v8 = *(const short8*)&X[(size_t)row * K + k0 + kk];
                *(short8*)&Xs[r * 40 + kk] = v8;
            }
        }
        // stage W^T tile (128 cols x 32 k)
        {
            int col = tid >> 1;
            int kh = (tid & 1) * 16;
            const u16* g = &WT[(size_t)col * K + k0 + kh];
            u16* d = &Ws[col * 40 + kh];
            *(short8*)d = *(const short8*)g;
            *(short8*)(d + 8) = *(const short8*)(g + 8);
        }
        __syncthreads();
        short8 a = *(const short8*)&Xs[(wv * 16 + rsel) * 40 + kgrp];
#pragma unroll
        for (int c = 0; c < 8; ++c) {
            short8 b = *(const short8*)&Ws[(c * 16 + rsel) * 40 + kgrp];
            acc[c] = __builtin_amdgcn_mfma_f32_16x16x32_bf16(a, b, acc[c], 0, 0, 0);
        }
        __syncthreads();
    }
    // D layout: col = lane&15, row = (lane>>4)*4 + reg
#pragma unroll
    for (int r = 0; r < 4; ++r) {
        int row = row0 + wv * 16 + (lane >> 4) * 4 + r;
        if (row < N) {
#pragma unroll
            for (int c = 0; c < 8; ++c)
                Y[(size_t)row * 128 + c * 16 + rsel] = f2bf(acc[c][r]);
        }
    }
}

// ========== gather core: one node per wave, 4 edge-slots x 16 feature-lanes ==========
// a[8] accumulates sum_j dinv[s_j] * XW[s_j, q*8 .. q*8+7]
#define GATHER_CORE(XW, rowptr, csr, dinv, node, q, es, a)                         \
    int beg = rowptr[node], end = rowptr[node + 1];                                \
    float a[8];                                                                    \
    _Pragma("unroll") for (int i = 0; i < 8; ++i) a[i] = 0.f;                      \
    {                                                                              \
        int j = beg + es;                                                          \
        for (; j + 4 < end; j += 8) {                                              \
            int s0 = csr[j], s1 = csr[j + 4];                                      \
            float w0 = dinv[s0], w1 = dinv[s1];                                    \
            short8 r0 = *(const short8*)&XW[(size_t)s0 * 128 + q * 8];             \
            short8 r1 = *(const short8*)&XW[(size_t)s1 * 128 + q * 8];             \
            _Pragma("unroll") for (int i = 0; i < 8; ++i)                          \
                a[i] += bfc(r0[i]) * w0 + bfc(r1[i]) * w1;                         \
        }                                                                          \
        if (j < end) {                                                             \
            int s = csr[j];                                                        \
            float w = dinv[s];                                                     \
            short8 r = *(const short8*)&XW[(size_t)s * 128 + q * 8];               \
            _Pragma("unroll") for (int i = 0; i < 8; ++i) a[i] += bfc(r[i]) * w;   \
        }                                                                          \
    }                                                                              \
    _Pragma("unroll") for (int i = 0; i < 8; ++i) {                                \
        a[i] += __shfl_xor(a[i], 16);                                              \
        a[i] += __shfl_xor(a[i], 32);                                              \
    }

// ===== layer 1: gather + self + bias + LN + ReLU -> H bf16 =====
__global__ __launch_bounds__(256) void k_gather_ln_relu(const u16* __restrict__ XW,
                                                        const int* __restrict__ rowptr,
                                                        const int* __restrict__ csr,
                                                        const float* __restrict__ dinv,
                                                        const float* __restrict__ b,
                                                        const float* __restrict__ gamma,
                                                        const float* __restrict__ beta,
                                                        u16* __restrict__ H, int N) {
    int node = blockIdx.x * 4 + (threadIdx.x >> 6);
    int lane = threadIdx.x & 63;
    int q = lane & 15;
    int es = lane >> 4;
    if (node >= N) return;
    float di = dinv[node];
    GATHER_CORE(XW, rowptr, csr, dinv, node, q, es, a)
    short8 us = *(const short8*)&XW[(size_t)node * 128 + q * 8];
    float d2 = di * di;
    float4 b0 = *(const float4*)&b[q * 8];
    float4 b1 = *(const float4*)&b[q * 8 + 4];
    float v[8];
#pragma unroll
    for (int i = 0; i < 8; ++i) {
        float bb = (i < 4) ? ((const float*)&b0)[i] : ((const float*)&b1)[i - 4];
        v[i] = a[i] * di + bfc(us[i]) * d2 + bb;
    }
    float s = 0.f, sq = 0.f;
#pragma unroll
    for (int i = 0; i < 8; ++i) { s += v[i]; sq += v[i] * v[i]; }
#pragma unroll
    for (int off = 8; off; off >>= 1) {
        s  += __shfl_xor(s, off);
        sq += __shfl_xor(sq, off);
    }
    float mu  = s * (1.f / 128.f);
    float var = sq * (1.f / 128.f) - mu * mu;
    float rr  = rsqrtf(var + 1e-5f);
    float4 g0 = *(const float4*)&gamma[q * 8];
    float4 g1 = *(const float4*)&gamma[q * 8 + 4];
    float4 e0 = *(const float4*)&beta[q * 8];
    float4 e1 = *(const float4*)&beta[q * 8 + 4];
    if (es == 0) {
        union { u16 us[8]; short8 v8; } o;
#pragma unroll
        for (int i = 0; i < 8; ++i) {
            float gg = (i < 4) ? ((const float*)&g0)[i] : ((const float*)&g1)[i - 4];
            float ee = (i < 4) ? ((const float*)&e0)[i] : ((const float*)&e1)[i - 4];
            o.us[i] = f2bf(fmaxf((v[i] - mu) * rr * gg + ee, 0.f));
        }
        *(short8*)&H[(size_t)node * 128 + q * 8] = o.v8;
    }
}

// ===== layer 2: gather + self + bias + ReLU -> H bf16 =====
__global__ __launch_bounds__(256) void k_gather_relu(const u16* __restrict__ XW,
                                                     const int* __restrict__ rowptr,
                                                     const int* __restrict__ csr,
                                                     const float* __restrict__ dinv,
                                                     const float* __restrict__ b,
                                                     u16* __restrict__ H, int N) {
    int node = blockIdx.x * 4 + (threadIdx.x >> 6);
    int lane = threadIdx.x & 63;
    int q = lane & 15;
    int es = lane >> 4;
    if (node >= N) return;
    float di = dinv[node];
    GATHER_CORE(XW, rowptr, csr, dinv, node, q, es, a)
    if (es != 0) return;
    short8 us = *(const short8*)&XW[(size_t)node * 128 + q * 8];
    float d2 = di * di;
    float4 b0 = *(const float4*)&b[q * 8];
    float4 b1 = *(const float4*)&b[q * 8 + 4];
    union { u16 us[8]; short8 v8; } o;
#pragma unroll
    for (int i = 0; i < 8; ++i) {
        float bb = (i < 4) ? ((const float*)&b0)[i] : ((const float*)&b1)[i - 4];
        o.us[i] = f2bf(fmaxf(a[i] * di + bfc(us[i]) * d2 + bb, 0.f));
    }
    *(short8*)&H[(size_t)node * 128 + q * 8] = o.v8;
}

// ===== layer 3 gather + ReLU fused with layer-4 W4 dot -> xw4 f32 =====
__global__ __launch_bounds__(256) void k_gather_dot(const u16* __restrict__ XW,
                                                    const int* __restrict__ rowptr,
                                                    const int* __restrict__ csr,
                                                    const float* __restrict__ dinv,
                                                    const float* __restrict__ b,
                                                    const float* __restrict__ W4,
                                                    float* __restrict__ XW4, int N) {
    int node = blockIdx.x * 4 + (threadIdx.x >> 6);
    int lane = threadIdx.x & 63;
    int q = lane & 15;
    int es = lane >> 4;
    if (node >= N) return;
    float di = dinv[node];
    GATHER_CORE(XW, rowptr, csr, dinv, node, q, es, a)
    short8 us = *(const short8*)&XW[(size_t)node * 128 + q * 8];
    float d2 = di * di;
    float4 b0 = *(const float4*)&b[q * 8];
    float4 b1 = *(const float4*)&b[q * 8 + 4];
    float4 w0 = *(const float4*)&W4[q * 8];
    float4 w1 = *(const float4*)&W4[q * 8 + 4];
    float t = 0.f;
#pragma unroll
    for (int i = 0; i < 8; ++i) {
        float bb = (i < 4) ? ((const float*)&b0)[i] : ((const float*)&b1)[i - 4];
        float ww = (i < 4) ? ((const float*)&w0)[i] : ((const float*)&w1)[i - 4];
        float v = fmaxf(a[i] * di + bfc(us[i]) * d2 + bb, 0.f);
        t += v * ww;
    }
#pragma unroll
    for (int off = 8; off; off >>= 1) t += __shfl_xor(t, off);
    if (lane == 0) XW4[node] = t;
}

// ===== final: out = agg(xw4)*norm + self + b4; 16 lanes per node =====
__global__ __launch_bounds__(256) void k_final_scalar(const float* __restrict__ XW4,
                                                      const int* __restrict__ rowptr,
                                                      const int* __restrict__ csr,
                                                      const float* __restrict__ dinv,
                                                      const float* __restrict__ b4,
                                                      float* __restrict__ OUT, int N) {
    int node = blockIdx.x * 16 + (threadIdx.x >> 4);
    int q = threadIdx.x & 15;
    if (node >= N) return;
    int beg = rowptr[node], end = rowptr[node + 1];
    float acc = 0.f;
    for (int j = beg + q; j < end; j += 16) {
        int s = csr[j];
        acc += XW4[s] * dinv[s];
    }
#pragma unroll
    for (int off = 8; off; off >>= 1) acc += __shfl_xor(acc, off);
    if (q == 0) {
        float di = dinv[node];
        OUT[node] = acc * di + XW4[node] * di * di + b4[0];
    }
}

// ================= launch =================
static inline size_t alignup(size_t x) { return (x + 255) & ~(size_t)255; }

extern "C" void kernel_launch(void* const* d_in, const int* in_sizes, int n_in,
                              void* d_out, int out_size, void* d_ws, size_t ws_size,
                              hipStream_t stream) {
    const float* x      = (const float*)d_in[0];
    const float* W1     = (const float*)d_in[1];
    const float* b1     = (const float*)d_in[2];
    const float* gamma1 = (const float*)d_in[3];
    const float* beta1  = (const float*)d_in[4];
    const float* W2     = (const float*)d_in[5];
    const float* b2     = (const float*)d_in[6];
    const float* W3     = (const float*)d_in[7];
    const float* b3     = (const float*)d_in[8];
    const float* W4     = (const float*)d_in[9];
    const float* b4     = (const float*)d_in[10];
    const int*   ei     = (const int*)d_in[11];

    const int N = in_sizes[0] / D_IN;     // 50000
    const int E = in_sizes[11] / 2;       // 625000
    const int* src = ei;
    const int* dst = ei + E;

    char* ws = (char*)d_ws;
    size_t off = 0;
    int*   deg_cur = (int*)(ws + off);   off += alignup((size_t)N * 4);
    int*   rowptr  = (int*)(ws + off);   off += alignup((size_t)(N + 1) * 4);
    int*   bsum    = (int*)(ws + off);   off += alignup(256 * 4);
    float* dinv    = (float*)(ws + off); off += alignup((size_t)N * 4);
    float* xw4     = (float*)(ws + off); off += alignup((size_t)N * 4);
    int*   csr     = (int*)(ws + off);   off += alignup((size_t)E * 4);
    u16*   WT1     = (u16*)(ws + off);   off += alignup((size_t)128 * 512 * 2);
    u16*   WT2     = (u16*)(ws + off);   off += alignup((size_t)128 * 128 * 2);
    u16*   WT3     = (u16*)(ws + off);   off += alignup((size_t)128 * 128 * 2);
    u16*   XW      = (u16*)(ws + off);   off += alignup((size_t)N * 128 * 2);
    u16*   H       = (u16*)(ws + off);

    const int scanBlocks = (N + 255) / 256;

    // ---- CSR build
    hipMemsetAsync(deg_cur, 0, (size_t)N * 4, stream);
    k_deg_int<<<(E + 255) / 256, 256, 0, stream>>>(dst, deg_cur, E);
    k_scan_block<<<scanBlocks, 256, 0, stream>>>(deg_cur, rowptr, bsum, N);
    k_scan_partials<<<1, 256, 0, stream>>>(bsum, scanBlocks);
    k_apply_offset<<<scanBlocks, 256, 0, stream>>>(rowptr, bsum, deg_cur, dinv, N, E);
    k_fill_csr<<<(E + 255) / 256, 256, 0, stream>>>(src, dst, deg_cur, csr, E);

    // ---- weights -> bf16 transposed (single launch)
    k_wt_all<<<(65536 + 32768 + 255) / 256, 256, 0, stream>>>(W1, W2, W3, WT1, WT2, WT3);

    const int gemmGrid   = (N + 63) / 64;
    const int gatherGrid = (N + 3) / 4;

    // ---- Layer 1
    k_gemm_mfma<512, float><<<gemmGrid, 256, 0, stream>>>(x, WT1, XW, N);
    k_gather_ln_relu<<<gatherGrid, 256, 0, stream>>>(XW, rowptr, csr, dinv,
                                                     b1, gamma1, beta1, H, N);
    // ---- Layer 2
    k_gemm_mfma<128, u16><<<gemmGrid, 256, 0, stream>>>(H, WT2, XW, N);
    k_gather_relu<<<gatherGrid, 256, 0, stream>>>(XW, rowptr, csr, dinv, b2, H, N);
    // ---- Layer 3 (+ fused W4 dot)
    k_gemm_mfma<128, u16><<<gemmGrid, 256, 0, stream>>>(H, WT3, XW, N);
    k_gather_dot<<<gatherGrid, 256, 0, stream>>>(XW, rowptr, csr, dinv, b3, W4, xw4, N);
    // ---- Layer 4 aggregate
    k_final_scalar<<<(N + 15) / 16, 256, 0, stream>>>(xw4, rowptr, csr, dinv,
                                                      b4, (float*)d_out, N);
}

// Round 11
// 374.236 us; speedup vs baseline: 9.5268x; 1.0030x over previous
//
#include <hip/hip_runtime.h>
#include <hip/hip_bf16.h>
#include <cstdint>

#define D_IN 512
#define D_HID 128

typedef unsigned short u16;
typedef unsigned int u32;
typedef __attribute__((ext_vector_type(8))) short short8;
typedef __attribute__((ext_vector_type(4))) float f32x4;

__device__ __forceinline__ u16 f2bf(float f) {
    u32 u = __float_as_uint(f);
    u = (u + 0x7FFFu + ((u >> 16) & 1u)) >> 16;
    return (u16)u;
}
__device__ __forceinline__ float bfc(short x) {
    return __uint_as_float(((u32)(u16)x) << 16);
}

// ================= CSR build =================
__global__ __launch_bounds__(256) void k_deg_int(const int* __restrict__ dst,
                                                 int* __restrict__ deg, int E) {
    int e = blockIdx.x * 256 + threadIdx.x;
    if (e < E) atomicAdd(&deg[dst[e]], 1);
}

__global__ __launch_bounds__(256) void k_scan_block(const int* __restrict__ deg,
                                                    int* __restrict__ rowptr,
                                                    int* __restrict__ bsum, int N) {
    __shared__ int sh[256];
    int i = blockIdx.x * 256 + threadIdx.x;
    int v = (i < N) ? deg[i] : 0;
    sh[threadIdx.x] = v;
    __syncthreads();
#pragma unroll
    for (int off = 1; off < 256; off <<= 1) {
        int t = (threadIdx.x >= off) ? sh[threadIdx.x - off] : 0;
        __syncthreads();
        sh[threadIdx.x] += t;
        __syncthreads();
    }
    int incl = sh[threadIdx.x];
    if (i < N) rowptr[i] = incl - v;
    if (threadIdx.x == 255) bsum[blockIdx.x] = incl;
}

// apply block offsets (re-scanning the P partials locally), init cursor, dinv
__global__ __launch_bounds__(256) void k_apply_offset(int* __restrict__ rowptr,
                                                      const int* __restrict__ bsum,
                                                      int* __restrict__ deg_cursor,
                                                      float* __restrict__ dinv,
                                                      int N, int E, int P) {
    __shared__ int sh[256];
    int v = (threadIdx.x < P) ? bsum[threadIdx.x] : 0;
    sh[threadIdx.x] = v;
    __syncthreads();
#pragma unroll
    for (int off = 1; off < 256; off <<= 1) {
        int t = (threadIdx.x >= off) ? sh[threadIdx.x - off] : 0;
        __syncthreads();
        sh[threadIdx.x] += t;
        __syncthreads();
    }
    int boff = (blockIdx.x == 0) ? 0 : sh[blockIdx.x - 1];  // exclusive offset for this block
    int i = blockIdx.x * 256 + threadIdx.x;
    if (i == 0) rowptr[N] = E;
    if (i >= N) return;
    int dv = deg_cursor[i];
    int rp = rowptr[i] + boff;
    rowptr[i] = rp;
    deg_cursor[i] = rp;
    dinv[i] = rsqrtf((float)dv + 1.0f);
}

__global__ __launch_bounds__(256) void k_fill_csr(const int* __restrict__ src,
                                                  const int* __restrict__ dst,
                                                  int* __restrict__ cursor,
                                                  int* __restrict__ csr, int E) {
    int e = blockIdx.x * 256 + threadIdx.x;
    if (e >= E) return;
    int pos = atomicAdd(&cursor[dst[e]], 1);
    csr[pos] = src[e];
}

// ============ all weights -> bf16 transposed, one launch ============
// WT[c][k] = bf16(W[k][c])
__global__ __launch_bounds__(256) void k_wt_all(const float* __restrict__ W1,
                                                const float* __restrict__ W2,
                                                const float* __restrict__ W3,
                                                u16* __restrict__ WT1,
                                                u16* __restrict__ WT2,
                                                u16* __restrict__ WT3) {
    int t = blockIdx.x * 256 + threadIdx.x;
    if (t < 65536) {                       // 128 cols x 512 k
        int c = t >> 9, k = t & 511;
        WT1[t] = f2bf(W1[(size_t)k * 128 + c]);
    } else if (t < 65536 + 16384) {
        int u = t - 65536;
        int c = u >> 7, k = u & 127;
        WT2[u] = f2bf(W2[(size_t)k * 128 + c]);
    } else if (t < 65536 + 32768) {
        int u = t - 65536 - 16384;
        int c = u >> 7, k = u & 127;
        WT3[u] = f2bf(W3[(size_t)k * 128 + c]);
    }
}

// ====== MFMA GEMM: Y[N,128](bf16) = (X[N,K] @ W[K,128]) * dinv[row]  (pre-scaled) ======
// block = 64 rows x 128 cols, 4 waves (16 rows each), K-step 32
template <int K, typename TI>
__global__ __launch_bounds__(256) void k_gemm_mfma(const TI* __restrict__ X,
                                                   const u16* __restrict__ WT,
                                                   const float* __restrict__ dinv,
                                                   u16* __restrict__ Y, int N) {
    __shared__ u16 Xs[64 * 40];
    __shared__ u16 Ws[128 * 40];
    const int tid = threadIdx.x;
    const int wv = tid >> 6;
    const int lane = tid & 63;
    const int row0 = blockIdx.x * 64;
    const int rsel = lane & 15;
    const int kgrp = (lane >> 4) * 8;

    f32x4 acc[8];
#pragma unroll
    for (int c = 0; c < 8; ++c) acc[c] = (f32x4){0.f, 0.f, 0.f, 0.f};

    for (int k0 = 0; k0 < K; k0 += 32) {
        // stage X tile (64 rows x 32 k) -> bf16 LDS
        {
            int r = tid >> 2;
            int kk = (tid & 3) * 8;
            int row = row0 + r;
            if constexpr (sizeof(TI) == 4) {
                float v[8];
                if (row < N) {
                    float4 p0 = *(const float4*)&X[(size_t)row * K + k0 + kk];
                    float4 p1 = *(const float4*)&X[(size_t)row * K + k0 + kk + 4];
                    v[0] = p0.x; v[1] = p0.y; v[2] = p0.z; v[3] = p0.w;
                    v[4] = p1.x; v[5] = p1.y; v[6] = p1.z; v[7] = p1.w;
                } else {
#pragma unroll
                    for (int i = 0; i < 8; ++i) v[i] = 0.f;
                }
                union { u16 us[8]; short8 v8; } tmp;
#pragma unroll
                for (int i = 0; i < 8; ++i) tmp.us[i] = f2bf(v[i]);
                *(short8*)&Xs[r * 40 + kk] = tmp.v8;
            } else {
                short8 v8 = {};
                if (row < N) v8 = *(const short8*)&X[(size_t)row * K + k0 + kk];
                *(short8*)&Xs[r * 40 + kk] = v8;
            }
        }
        // stage W^T tile (128 cols x 32 k)
        {
            int col = tid >> 1;
            int kh = (tid & 1) * 16;
            const u16* g = &WT[(size_t)col * K + k0 + kh];
            u16* d = &Ws[col * 40 + kh];
            *(short8*)d = *(const short8*)g;
            *(short8*)(d + 8) = *(const short8*)(g + 8);
        }
        __syncthreads();
        short8 a = *(const short8*)&Xs[(wv * 16 + rsel) * 40 + kgrp];
#pragma unroll
        for (int c = 0; c < 8; ++c) {
            short8 b = *(const short8*)&Ws[(c * 16 + rsel) * 40 + kgrp];
            acc[c] = __builtin_amdgcn_mfma_f32_16x16x32_bf16(a, b, acc[c], 0, 0, 0);
        }
        __syncthreads();
    }
    // D layout: col = lane&15, row = (lane>>4)*4 + reg ; scale by dinv[row]
#pragma unroll
    for (int r = 0; r < 4; ++r) {
        int row = row0 + wv * 16 + (lane >> 4) * 4 + r;
        if (row < N) {
            float ds = dinv[row];
#pragma unroll
            for (int c = 0; c < 8; ++c)
                Y[(size_t)row * 128 + c * 16 + rsel] = f2bf(acc[c][r] * ds);
        }
    }
}

// ===== gather core (pre-scaled XW'): pure row-sum, 4 edge-slots x 16 lanes =====
// 3-tier coverage: 16 / 8 / 4 edges per dependent-latency round
#define GATHER_CORE(XW, rowptr, csr, node, q, es, a)                               \
    int beg = rowptr[node], end = rowptr[node + 1];                                \
    float a[8];                                                                    \
    _Pragma("unroll") for (int i = 0; i < 8; ++i) a[i] = 0.f;                      \
    {                                                                              \
        int j = beg + es;                                                          \
        for (; j + 12 < end; j += 16) {                                            \
            int s0 = csr[j], s1 = csr[j + 4], s2 = csr[j + 8], s3 = csr[j + 12];   \
            short8 r0 = *(const short8*)&XW[(size_t)s0 * 128 + q * 8];             \
            short8 r1 = *(const short8*)&XW[(size_t)s1 * 128 + q * 8];             \
            short8 r2 = *(const short8*)&XW[(size_t)s2 * 128 + q * 8];             \
            short8 r3 = *(const short8*)&XW[(size_t)s3 * 128 + q * 8];             \
            _Pragma("unroll") for (int i = 0; i < 8; ++i)                          \
                a[i] += (bfc(r0[i]) + bfc(r1[i])) + (bfc(r2[i]) + bfc(r3[i]));     \
        }                                                                          \
        if (j + 4 < end) {                                                         \
            int s0 = csr[j], s1 = csr[j + 4];                                      \
            short8 r0 = *(const short8*)&XW[(size_t)s0 * 128 + q * 8];             \
            short8 r1 = *(const short8*)&XW[(size_t)s1 * 128 + q * 8];             \
            _Pragma("unroll") for (int i = 0; i < 8; ++i)                          \
                a[i] += bfc(r0[i]) + bfc(r1[i]);                                   \
            j += 8;                                                                \
        }                                                                          \
        if (j < end) {                                                             \
            int s = csr[j];                                                        \
            short8 r = *(const short8*)&XW[(size_t)s * 128 + q * 8];               \
            _Pragma("unroll") for (int i = 0; i < 8; ++i) a[i] += bfc(r[i]);       \
        }                                                                          \
    }                                                                              \
    _Pragma("unroll") for (int i = 0; i < 8; ++i) {                                \
        a[i] += __shfl_xor(a[i], 16);                                              \
        a[i] += __shfl_xor(a[i], 32);                                              \
    }

// ===== layer 1: gather + self + bias + LN + ReLU -> H bf16 =====
__global__ __launch_bounds__(256) void k_gather_ln_relu(const u16* __restrict__ XW,
                                                        const int* __restrict__ rowptr,
                                                        const int* __restrict__ csr,
                                                        const float* __restrict__ dinv,
                                                        const float* __restrict__ b,
                                                        const float* __restrict__ gamma,
                                                        const float* __restrict__ beta,
                                                        u16* __restrict__ H, int N) {
    int node = blockIdx.x * 4 + (threadIdx.x >> 6);
    int lane = threadIdx.x & 63;
    int q = lane & 15;
    int es = lane >> 4;
    if (node >= N) return;
    float di = dinv[node];
    GATHER_CORE(XW, rowptr, csr, node, q, es, a)
    short8 us = *(const short8*)&XW[(size_t)node * 128 + q * 8];
    float4 b0 = *(const float4*)&b[q * 8];
    float4 b1 = *(const float4*)&b[q * 8 + 4];
    float v[8];
#pragma unroll
    for (int i = 0; i < 8; ++i) {
        float bb = (i < 4) ? ((const float*)&b0)[i] : ((const float*)&b1)[i - 4];
        v[i] = (a[i] + bfc(us[i])) * di + bb;
    }
    float s = 0.f, sq = 0.f;
#pragma unroll
    for (int i = 0; i < 8; ++i) { s += v[i]; sq += v[i] * v[i]; }
#pragma unroll
    for (int off = 8; off; off >>= 1) {
        s  += __shfl_xor(s, off);
        sq += __shfl_xor(sq, off);
    }
    float mu  = s * (1.f / 128.f);
    float var = sq * (1.f / 128.f) - mu * mu;
    float rr  = rsqrtf(var + 1e-5f);
    float4 g0 = *(const float4*)&gamma[q * 8];
    float4 g1 = *(const float4*)&gamma[q * 8 + 4];
    float4 e0 = *(const float4*)&beta[q * 8];
    float4 e1 = *(const float4*)&beta[q * 8 + 4];
    if (es == 0) {
        union { u16 us[8]; short8 v8; } o;
#pragma unroll
        for (int i = 0; i < 8; ++i) {
            float gg = (i < 4) ? ((const float*)&g0)[i] : ((const float*)&g1)[i - 4];
            float ee = (i < 4) ? ((const float*)&e0)[i] : ((const float*)&e1)[i - 4];
            o.us[i] = f2bf(fmaxf((v[i] - mu) * rr * gg + ee, 0.f));
        }
        *(short8*)&H[(size_t)node * 128 + q * 8] = o.v8;
    }
}

// ===== layer 2: gather + self + bias + ReLU -> H bf16 =====
__global__ __launch_bounds__(256) void k_gather_relu(const u16* __restrict__ XW,
                                                     const int* __restrict__ rowptr,
                                                     const int* __restrict__ csr,
                                                     const float* __restrict__ dinv,
                                                     const float* __restrict__ b,
                                                     u16* __restrict__ H, int N) {
    int node = blockIdx.x * 4 + (threadIdx.x >> 6);
    int lane = threadIdx.x & 63;
    int q = lane & 15;
    int es = lane >> 4;
    if (node >= N) return;
    float di = dinv[node];
    GATHER_CORE(XW, rowptr, csr, node, q, es, a)
    if (es != 0) return;
    short8 us = *(const short8*)&XW[(size_t)node * 128 + q * 8];
    float4 b0 = *(const float4*)&b[q * 8];
    float4 b1 = *(const float4*)&b[q * 8 + 4];
    union { u16 us[8]; short8 v8; } o;
#pragma unroll
    for (int i = 0; i < 8; ++i) {
        float bb = (i < 4) ? ((const float*)&b0)[i] : ((const float*)&b1)[i - 4];
        o.us[i] = f2bf(fmaxf((a[i] + bfc(us[i])) * di + bb, 0.f));
    }
    *(short8*)&H[(size_t)node * 128 + q * 8] = o.v8;
}

// ===== layer 3 gather + ReLU fused with layer-4 W4 dot -> XW4' = (h3 . W4) * dinv =====
__global__ __launch_bounds__(256) void k_gather_dot(const u16* __restrict__ XW,
                                                    const int* __restrict__ rowptr,
                                                    const int* __restrict__ csr,
                                                    const float* __restrict__ dinv,
                                                    const float* __restrict__ b,
                                                    const float* __restrict__ W4,
                                                    float* __restrict__ XW4, int N) {
    int node = blockIdx.x * 4 + (threadIdx.x >> 6);
    int lane = threadIdx.x & 63;
    int q = lane & 15;
    int es = lane >> 4;
    if (node >= N) return;
    float di = dinv[node];
    GATHER_CORE(XW, rowptr, csr, node, q, es, a)
    short8 us = *(const short8*)&XW[(size_t)node * 128 + q * 8];
    float4 b0 = *(const float4*)&b[q * 8];
    float4 b1 = *(const float4*)&b[q * 8 + 4];
    float4 w0 = *(const float4*)&W4[q * 8];
    float4 w1 = *(const float4*)&W4[q * 8 + 4];
    float t = 0.f;
#pragma unroll
    for (int i = 0; i < 8; ++i) {
        float bb = (i < 4) ? ((const float*)&b0)[i] : ((const float*)&b1)[i - 4];
        float ww = (i < 4) ? ((const float*)&w0)[i] : ((const float*)&w1)[i - 4];
        float v = fmaxf((a[i] + bfc(us[i])) * di + bb, 0.f);
        t += v * ww;
    }
#pragma unroll
    for (int off = 8; off; off >>= 1) t += __shfl_xor(t, off);
    if (lane == 0) XW4[node] = t * di;     // pre-scaled
}

// ===== final: out = di * (sum_nbrs XW4'[s] + XW4'[node]) + b4 =====
__global__ __launch_bounds__(256) void k_final_scalar(const float* __restrict__ XW4,
                                                      const int* __restrict__ rowptr,
                                                      const int* __restrict__ csr,
                                                      const float* __restrict__ dinv,
                                                      const float* __restrict__ b4,
                                                      float* __restrict__ OUT, int N) {
    int node = blockIdx.x * 16 + (threadIdx.x >> 4);
    int q = threadIdx.x & 15;
    if (node >= N) return;
    int beg = rowptr[node], end = rowptr[node + 1];
    float acc = 0.f;
    for (int j = beg + q; j < end; j += 16) {
        acc += XW4[csr[j]];
    }
#pragma unroll
    for (int off = 8; off; off >>= 1) acc += __shfl_xor(acc, off);
    if (q == 0) {
        OUT[node] = dinv[node] * (acc + XW4[node]) + b4[0];
    }
}

// ================= launch =================
static inline size_t alignup(size_t x) { return (x + 255) & ~(size_t)255; }

extern "C" void kernel_launch(void* const* d_in, const int* in_sizes, int n_in,
                              void* d_out, int out_size, void* d_ws, size_t ws_size,
                              hipStream_t stream) {
    const float* x      = (const float*)d_in[0];
    const float* W1     = (const float*)d_in[1];
    const float* b1     = (const float*)d_in[2];
    const float* gamma1 = (const float*)d_in[3];
    const float* beta1  = (const float*)d_in[4];
    const float* W2     = (const float*)d_in[5];
    const float* b2     = (const float*)d_in[6];
    const float* W3     = (const float*)d_in[7];
    const float* b3     = (const float*)d_in[8];
    const float* W4     = (const float*)d_in[9];
    const float* b4     = (const float*)d_in[10];
    const int*   ei     = (const int*)d_in[11];

    const int N = in_sizes[0] / D_IN;     // 50000
    const int E = in_sizes[11] / 2;       // 625000
    const int* src = ei;
    const int* dst = ei + E;

    char* ws = (char*)d_ws;
    size_t off = 0;
    int*   deg_cur = (int*)(ws + off);   off += alignup((size_t)N * 4);
    int*   rowptr  = (int*)(ws + off);   off += alignup((size_t)(N + 1) * 4);
    int*   bsum    = (int*)(ws + off);   off += alignup(256 * 4);
    float* dinv    = (float*)(ws + off); off += alignup((size_t)N * 4);
    float* xw4     = (float*)(ws + off); off += alignup((size_t)N * 4);
    int*   csr     = (int*)(ws + off);   off += alignup((size_t)E * 4);
    u16*   WT1     = (u16*)(ws + off);   off += alignup((size_t)128 * 512 * 2);
    u16*   WT2     = (u16*)(ws + off);   off += alignup((size_t)128 * 128 * 2);
    u16*   WT3     = (u16*)(ws + off);   off += alignup((size_t)128 * 128 * 2);
    u16*   XW      = (u16*)(ws + off);   off += alignup((size_t)N * 128 * 2);
    u16*   H       = (u16*)(ws + off);

    const int scanBlocks = (N + 255) / 256;   // 196

    // ---- CSR build (4 dispatches + memset)
    hipMemsetAsync(deg_cur, 0, (size_t)N * 4, stream);
    k_deg_int<<<(E + 255) / 256, 256, 0, stream>>>(dst, deg_cur, E);
    k_scan_block<<<scanBlocks, 256, 0, stream>>>(deg_cur, rowptr, bsum, N);
    k_apply_offset<<<scanBlocks, 256, 0, stream>>>(rowptr, bsum, deg_cur, dinv,
                                                   N, E, scanBlocks);
    k_fill_csr<<<(E + 255) / 256, 256, 0, stream>>>(src, dst, deg_cur, csr, E);

    // ---- weights -> bf16 transposed (single launch)
    k_wt_all<<<(65536 + 32768 + 255) / 256, 256, 0, stream>>>(W1, W2, W3, WT1, WT2, WT3);

    const int gemmGrid   = (N + 63) / 64;
    const int gatherGrid = (N + 3) / 4;

    // ---- Layer 1
    k_gemm_mfma<512, float><<<gemmGrid, 256, 0, stream>>>(x, WT1, dinv, XW, N);
    k_gather_ln_relu<<<gatherGrid, 256, 0, stream>>>(XW, rowptr, csr, dinv,
                                                     b1, gamma1, beta1, H, N);
    // ---- Layer 2
    k_gemm_mfma<128, u16><<<gemmGrid, 256, 0, stream>>>(H, WT2, dinv, XW, N);
    k_gather_relu<<<gatherGrid, 256, 0, stream>>>(XW, rowptr, csr, dinv, b2, H, N);
    // ---- Layer 3 (+ fused W4 dot, pre-scaled)
    k_gemm_mfma<128, u16><<<gemmGrid, 256, 0, stream>>>(H, WT3, dinv, XW, N);
    k_gather_dot<<<gatherGrid, 256, 0, stream>>>(XW, rowptr, csr, dinv, b3, W4, xw4, N);
    // ---- Layer 4 aggregate
    k_final_scalar<<<(N + 15) / 16, 256, 0, stream>>>(xw4, rowptr, csr, dinv,
                                                      b4, (float*)d_out, N);
}